// Round 3
// baseline (2392.517 us; speedup 1.0000x reference)
//
#include <hip/hip_runtime.h>

#define N_NODES 100000
#define F_IN 512
#define HID 256
#define NCLS 64
#define NHOPS 3
#define NEDGE 3200000

typedef unsigned short u16;
typedef __attribute__((ext_vector_type(8))) short bf16x8;
typedef __attribute__((ext_vector_type(4))) float f32x4;
typedef __attribute__((ext_vector_type(4))) unsigned int u32x4;

__device__ __forceinline__ u16 f2bf(float f) {
    unsigned int u = __float_as_uint(f);
    u += 0x7fffu + ((u >> 16) & 1u);   // round-to-nearest-even
    return (u16)(u >> 16);
}

// ---------------------------------------------------------------------------
// Kernel 0: convert + transpose weights to bf16.
// w1 [512][256] -> w1t [256][512] bf16 ; w2 [256][64] -> w2t [64][256] bf16
// ---------------------------------------------------------------------------
__global__ void convert_weights(const float* __restrict__ w1,
                                const float* __restrict__ w2,
                                u16* __restrict__ w1t, u16* __restrict__ w2t) {
    int t = blockIdx.x * 256 + threadIdx.x;
    if (t < F_IN * HID) {
        int k = t / HID, n = t % HID;           // coalesced read over n
        w1t[n * F_IN + k] = f2bf(w1[t]);
    } else if (t < F_IN * HID + HID * NCLS) {
        int i = t - F_IN * HID;
        int k = i / NCLS, n = i % NCLS;
        w2t[n * HID + k] = f2bf(w2[i]);
    }
}

// ---------------------------------------------------------------------------
// GEMM1: h = relu(x @ W1 + b1), bf16 out. Tile 128x256 (full N), 8 waves.
// Each wave computes a 64x64 quadrant via 4x4 fragments of 16x16x32 MFMA.
// x read as fp32 and converted to bf16 during LDS staging (x read exactly once).
// ---------------------------------------------------------------------------
__global__ __launch_bounds__(512) void gemm1_kernel(
    const float* __restrict__ x, const u16* __restrict__ w1t,
    const float* __restrict__ b1, u16* __restrict__ h)
{
    __shared__ u16 As[128][72];   // +8 pad -> 144B stride, 16B-aligned rows
    __shared__ u16 Bs[256][72];
    const int tid  = threadIdx.x;
    const int lane = tid & 63;
    const int wid  = tid >> 6;
    const int wr   = wid >> 2;    // 0..1
    const int wc   = wid & 3;     // 0..3
    const int row0 = blockIdx.x * 128;

    f32x4 acc[4][4] = {};

    // A-staging mapping: 128 rows x 64 k fp32 -> 16 elems/thread
    const int ar  = tid >> 2;            // 0..127
    const int aks = (tid & 3) * 16;      // 0/16/32/48
    int agrow = row0 + ar; if (agrow >= N_NODES) agrow = N_NODES - 1;
    const float* asrc = x + (size_t)agrow * F_IN + aks;

    // B-staging mapping: 256 n x 64 k bf16 -> 32 elems/thread
    const int bn  = tid >> 1;            // 0..255
    const int bks = (tid & 1) * 32;      // 0/32
    const u16* bsrc = w1t + bn * F_IN + bks;

    for (int k0 = 0; k0 < F_IN; k0 += 64) {
        alignas(16) u16 tmp[16];
        #pragma unroll
        for (int i = 0; i < 4; ++i) {
            f32x4 v = *(const f32x4*)(asrc + k0 + i * 4);
            tmp[i*4+0] = f2bf(v[0]); tmp[i*4+1] = f2bf(v[1]);
            tmp[i*4+2] = f2bf(v[2]); tmp[i*4+3] = f2bf(v[3]);
        }
        *(u32x4*)&As[ar][aks]     = *(const u32x4*)&tmp[0];
        *(u32x4*)&As[ar][aks + 8] = *(const u32x4*)&tmp[8];
        #pragma unroll
        for (int i = 0; i < 4; ++i)
            *(u32x4*)&Bs[bn][bks + i*8] = *(const u32x4*)(bsrc + k0 + i*8);
        __syncthreads();

        #pragma unroll
        for (int kk = 0; kk < 2; ++kk) {
            const int kb = kk*32 + (lane >> 4)*8;
            bf16x8 a[4], b[4];
            #pragma unroll
            for (int m = 0; m < 4; ++m)
                a[m] = *(const bf16x8*)&As[wr*64 + m*16 + (lane & 15)][kb];
            #pragma unroll
            for (int n = 0; n < 4; ++n)
                b[n] = *(const bf16x8*)&Bs[wc*64 + n*16 + (lane & 15)][kb];
            #pragma unroll
            for (int m = 0; m < 4; ++m)
                #pragma unroll
                for (int n = 0; n < 4; ++n)
                    acc[m][n] = __builtin_amdgcn_mfma_f32_16x16x32_bf16(
                        a[m], b[n], acc[m][n], 0, 0, 0);
        }
        __syncthreads();
    }

    // epilogue: C/D layout col=lane&15, row=(lane>>4)*4+rr
    const int cl    = lane & 15;
    const int rbase = (lane >> 4) * 4;
    #pragma unroll
    for (int n = 0; n < 4; ++n) {
        const int col  = wc*64 + n*16 + cl;
        const float bias = b1[col];
        #pragma unroll
        for (int m = 0; m < 4; ++m) {
            #pragma unroll
            for (int rr = 0; rr < 4; ++rr) {
                const int grow = row0 + wr*64 + m*16 + rbase + rr;
                if (grow < N_NODES) {
                    float v = acc[m][n][rr] + bias;
                    h[(size_t)grow * HID + col] = f2bf(v > 0.f ? v : 0.f);
                }
            }
        }
    }
}

// ---------------------------------------------------------------------------
// GEMM2: z = h @ W2 + b2 (fp32 to ws), out = prop_w[0] * z (d_out, full init).
// Tile 128x64 (full C), 4 waves, each wave 32x64 -> 2x4 fragments.
// ---------------------------------------------------------------------------
__global__ __launch_bounds__(256) void gemm2_kernel(
    const u16* __restrict__ h, const u16* __restrict__ w2t,
    const float* __restrict__ b2, const float* __restrict__ pw,
    float* __restrict__ z, float* __restrict__ out)
{
    __shared__ u16 As[128][72];
    __shared__ u16 Bs[64][72];
    const int tid  = threadIdx.x;
    const int lane = tid & 63;
    const int wid  = tid >> 6;           // 0..3, rows wid*32
    const int row0 = blockIdx.x * 128;

    f32x4 acc[2][4] = {};

    const int ar  = tid >> 1;            // 0..127
    const int aks = (tid & 1) * 32;
    int agrow = row0 + ar; if (agrow >= N_NODES) agrow = N_NODES - 1;
    const u16* asrc = h + (size_t)agrow * HID + aks;

    const int bn  = tid >> 2;            // 0..63
    const int bks = (tid & 3) * 16;
    const u16* bsrc = w2t + bn * HID + bks;

    for (int k0 = 0; k0 < HID; k0 += 64) {
        #pragma unroll
        for (int i = 0; i < 4; ++i)
            *(u32x4*)&As[ar][aks + i*8] = *(const u32x4*)(asrc + k0 + i*8);
        #pragma unroll
        for (int i = 0; i < 2; ++i)
            *(u32x4*)&Bs[bn][bks + i*8] = *(const u32x4*)(bsrc + k0 + i*8);
        __syncthreads();

        #pragma unroll
        for (int kk = 0; kk < 2; ++kk) {
            const int kb = kk*32 + (lane >> 4)*8;
            bf16x8 a[2], b[4];
            #pragma unroll
            for (int m = 0; m < 2; ++m)
                a[m] = *(const bf16x8*)&As[wid*32 + m*16 + (lane & 15)][kb];
            #pragma unroll
            for (int n = 0; n < 4; ++n)
                b[n] = *(const bf16x8*)&Bs[n*16 + (lane & 15)][kb];
            #pragma unroll
            for (int m = 0; m < 2; ++m)
                #pragma unroll
                for (int n = 0; n < 4; ++n)
                    acc[m][n] = __builtin_amdgcn_mfma_f32_16x16x32_bf16(
                        a[m], b[n], acc[m][n], 0, 0, 0);
        }
        __syncthreads();
    }

    const float pw0 = pw[0];
    const int cl    = lane & 15;
    const int rbase = (lane >> 4) * 4;
    #pragma unroll
    for (int n = 0; n < 4; ++n) {
        const int col = n*16 + cl;
        const float bias = b2[col];
        #pragma unroll
        for (int m = 0; m < 2; ++m) {
            #pragma unroll
            for (int rr = 0; rr < 4; ++rr) {
                const int grow = row0 + wid*32 + m*16 + rbase + rr;
                if (grow < N_NODES) {
                    float v = acc[m][n][rr] + bias;
                    size_t o = (size_t)grow * NCLS + col;
                    z[o]   = v;
                    out[o] = pw0 * v;
                }
            }
        }
    }
}

// ---------------------------------------------------------------------------
// Scatter: out[dst] += pw[l+1] * att[l][e] * z[src], all 3 hops.
// One wave per edge (lane = channel): idx/att loads wave-uniform, z/out 256B
// coalesced. Grid-stride over edges.
// ---------------------------------------------------------------------------
__global__ __launch_bounds__(256) void scatter_kernel(
    const int* __restrict__ eidx, const float* __restrict__ att,
    const float* __restrict__ pw, const float* __restrict__ z,
    float* __restrict__ out)
{
    const int t = blockIdx.x * 256 + threadIdx.x;
    const int c = t & 63;
    const int g = t >> 6;                            // wave id
    const int nw = (gridDim.x * 256) >> 6;
    #pragma unroll
    for (int l = 0; l < NHOPS; ++l) {
        const float w = pw[l + 1];
        const int* srcp = eidx + (size_t)l * 2 * NEDGE;
        const int* dstp = srcp + NEDGE;
        const float* al = att + (size_t)l * NEDGE;
        for (int e = g; e < NEDGE; e += nw) {
            const int s = srcp[e];
            const int d = dstp[e];
            const float a = w * al[e];
            const float v = a * z[(size_t)s * NCLS + c];
            atomicAdd(&out[(size_t)d * NCLS + c], v);
        }
    }
}

// ---------------------------------------------------------------------------
// log_softmax in-place on d_out, one wave per row (C = 64 = wave size).
// ---------------------------------------------------------------------------
__global__ __launch_bounds__(256) void logsoftmax_kernel(float* __restrict__ out) {
    const int lane = threadIdx.x & 63;
    const int row  = blockIdx.x * 4 + (threadIdx.x >> 6);
    if (row >= N_NODES) return;
    const size_t o = (size_t)row * NCLS + lane;
    const float v = out[o];
    float m = v;
    #pragma unroll
    for (int off = 32; off; off >>= 1) m = fmaxf(m, __shfl_xor(m, off));
    float s = __expf(v - m);
    #pragma unroll
    for (int off = 32; off; off >>= 1) s += __shfl_xor(s, off);
    out[o] = v - m - __logf(s);
}

// ---------------------------------------------------------------------------
extern "C" void kernel_launch(void* const* d_in, const int* in_sizes, int n_in,
                              void* d_out, int out_size, void* d_ws, size_t ws_size,
                              hipStream_t stream) {
    const float* x   = (const float*)d_in[0];
    const float* w1  = (const float*)d_in[1];
    const float* b1  = (const float*)d_in[2];
    const float* w2  = (const float*)d_in[3];
    const float* b2  = (const float*)d_in[4];
    const float* att = (const float*)d_in[5];
    const float* pw  = (const float*)d_in[6];
    const int* eidx  = (const int*)d_in[7];
    float* out = (float*)d_out;

    char* ws = (char*)d_ws;
    u16* w1t = (u16*)ws;                                   // 262144 B
    u16* w2t = (u16*)(ws + 262144);                        // 32768 B
    u16* h   = (u16*)(ws + 262144 + 32768);                // 51,200,000 B
    float* z = (float*)(ws + 262144 + 32768 + 51200000);   // 25,600,000 B

    const int nblk_m = (N_NODES + 127) / 128;              // 782

    convert_weights<<<(F_IN*HID + HID*NCLS + 255) / 256, 256, 0, stream>>>(w1, w2, w1t, w2t);
    gemm1_kernel<<<nblk_m, 512, 0, stream>>>(x, w1t, b1, h);
    gemm2_kernel<<<nblk_m, 256, 0, stream>>>(h, w2t, b2, pw, z, out);
    scatter_kernel<<<2048, 256, 0, stream>>>(eidx, att, pw, z, out);
    logsoftmax_kernel<<<(N_NODES + 3) / 4, 256, 0, stream>>>(out);
}

// Round 12
// 1659.689 us; speedup vs baseline: 1.4415x; 1.4415x over previous
//
#include <hip/hip_runtime.h>

#define NN 100000
#define F_IN 512
#define HID 256
#define NCLS 64
#define NHOPS 3
#define NE 3200000
#define NBLK1 98            // ceil(NN/1024)

typedef unsigned short u16;
typedef __attribute__((ext_vector_type(8))) short bf16x8;
typedef __attribute__((ext_vector_type(4))) float f32x4;
typedef __attribute__((ext_vector_type(4))) unsigned int u32x4;

__device__ __forceinline__ u16 f2bf(float f) {
    unsigned int u = __float_as_uint(f);
    u += 0x7fffu + ((u >> 16) & 1u);   // RNE
    return (u16)(u >> 16);
}
__device__ __forceinline__ float bf2f(u16 h) {
    return __uint_as_float(((unsigned int)h) << 16);
}

// ---------------------------------------------------------------------------
// weights -> bf16 transposed
// ---------------------------------------------------------------------------
__global__ void convert_weights(const float* __restrict__ w1,
                                const float* __restrict__ w2,
                                u16* __restrict__ w1t, u16* __restrict__ w2t) {
    int t = blockIdx.x * 256 + threadIdx.x;
    if (t < F_IN * HID) {
        int k = t / HID, n = t % HID;
        w1t[n * F_IN + k] = f2bf(w1[t]);
    } else if (t < F_IN * HID + HID * NCLS) {
        int i = t - F_IN * HID;
        int k = i / NCLS, n = i % NCLS;
        w2t[n * HID + k] = f2bf(w2[i]);
    }
}

// ---------------------------------------------------------------------------
// GEMM1: h = relu(x @ W1 + b1) bf16. 128x256 tile, 8 waves.
// ---------------------------------------------------------------------------
__global__ __launch_bounds__(512) void gemm1_kernel(
    const float* __restrict__ x, const u16* __restrict__ w1t,
    const float* __restrict__ b1, u16* __restrict__ h)
{
    __shared__ u16 As[128][72];
    __shared__ u16 Bs[256][72];
    const int tid  = threadIdx.x;
    const int lane = tid & 63;
    const int wid  = tid >> 6;
    const int wr   = wid >> 2;
    const int wc   = wid & 3;
    const int row0 = blockIdx.x * 128;

    f32x4 acc[4][4] = {};

    const int ar  = tid >> 2;
    const int aks = (tid & 3) * 16;
    int agrow = row0 + ar; if (agrow >= NN) agrow = NN - 1;
    const float* asrc = x + (size_t)agrow * F_IN + aks;

    const int bn  = tid >> 1;
    const int bks = (tid & 1) * 32;
    const u16* bsrc = w1t + bn * F_IN + bks;

    for (int k0 = 0; k0 < F_IN; k0 += 64) {
        alignas(16) u16 tmp[16];
        #pragma unroll
        for (int i = 0; i < 4; ++i) {
            f32x4 v = *(const f32x4*)(asrc + k0 + i * 4);
            tmp[i*4+0] = f2bf(v[0]); tmp[i*4+1] = f2bf(v[1]);
            tmp[i*4+2] = f2bf(v[2]); tmp[i*4+3] = f2bf(v[3]);
        }
        *(u32x4*)&As[ar][aks]     = *(const u32x4*)&tmp[0];
        *(u32x4*)&As[ar][aks + 8] = *(const u32x4*)&tmp[8];
        #pragma unroll
        for (int i = 0; i < 4; ++i)
            *(u32x4*)&Bs[bn][bks + i*8] = *(const u32x4*)(bsrc + k0 + i*8);
        __syncthreads();

        #pragma unroll
        for (int kk = 0; kk < 2; ++kk) {
            const int kb = kk*32 + (lane >> 4)*8;
            bf16x8 a[4], b[4];
            #pragma unroll
            for (int m = 0; m < 4; ++m)
                a[m] = *(const bf16x8*)&As[wr*64 + m*16 + (lane & 15)][kb];
            #pragma unroll
            for (int n = 0; n < 4; ++n)
                b[n] = *(const bf16x8*)&Bs[wc*64 + n*16 + (lane & 15)][kb];
            #pragma unroll
            for (int m = 0; m < 4; ++m)
                #pragma unroll
                for (int n = 0; n < 4; ++n)
                    acc[m][n] = __builtin_amdgcn_mfma_f32_16x16x32_bf16(
                        a[m], b[n], acc[m][n], 0, 0, 0);
        }
        __syncthreads();
    }

    const int cl    = lane & 15;
    const int rbase = (lane >> 4) * 4;
    #pragma unroll
    for (int n = 0; n < 4; ++n) {
        const int col  = wc*64 + n*16 + cl;
        const float bias = b1[col];
        #pragma unroll
        for (int m = 0; m < 4; ++m) {
            #pragma unroll
            for (int rr = 0; rr < 4; ++rr) {
                const int grow = row0 + wr*64 + m*16 + rbase + rr;
                if (grow < NN) {
                    float v = acc[m][n][rr] + bias;
                    h[(size_t)grow * HID + col] = f2bf(v > 0.f ? v : 0.f);
                }
            }
        }
    }
}

// ---------------------------------------------------------------------------
// GEMM2: zb = bf16(h @ W2 + b2). 128x64 tile, 4 waves.
// ---------------------------------------------------------------------------
__global__ __launch_bounds__(256) void gemm2_kernel(
    const u16* __restrict__ h, const u16* __restrict__ w2t,
    const float* __restrict__ b2, u16* __restrict__ zb)
{
    __shared__ u16 As[128][72];
    __shared__ u16 Bs[64][72];
    const int tid  = threadIdx.x;
    const int lane = tid & 63;
    const int wid  = tid >> 6;
    const int row0 = blockIdx.x * 128;

    f32x4 acc[2][4] = {};

    const int ar  = tid >> 1;
    const int aks = (tid & 1) * 32;
    int agrow = row0 + ar; if (agrow >= NN) agrow = NN - 1;
    const u16* asrc = h + (size_t)agrow * HID + aks;

    const int bn  = tid >> 2;
    const int bks = (tid & 3) * 16;
    const u16* bsrc = w2t + bn * HID + bks;

    for (int k0 = 0; k0 < HID; k0 += 64) {
        #pragma unroll
        for (int i = 0; i < 4; ++i)
            *(u32x4*)&As[ar][aks + i*8] = *(const u32x4*)(asrc + k0 + i*8);
        #pragma unroll
        for (int i = 0; i < 2; ++i)
            *(u32x4*)&Bs[bn][bks + i*8] = *(const u32x4*)(bsrc + k0 + i*8);
        __syncthreads();

        #pragma unroll
        for (int kk = 0; kk < 2; ++kk) {
            const int kb = kk*32 + (lane >> 4)*8;
            bf16x8 a[2], b[4];
            #pragma unroll
            for (int m = 0; m < 2; ++m)
                a[m] = *(const bf16x8*)&As[wid*32 + m*16 + (lane & 15)][kb];
            #pragma unroll
            for (int n = 0; n < 4; ++n)
                b[n] = *(const bf16x8*)&Bs[n*16 + (lane & 15)][kb];
            #pragma unroll
            for (int m = 0; m < 2; ++m)
                #pragma unroll
                for (int n = 0; n < 4; ++n)
                    acc[m][n] = __builtin_amdgcn_mfma_f32_16x16x32_bf16(
                        a[m], b[n], acc[m][n], 0, 0, 0);
        }
        __syncthreads();
    }

    const int cl    = lane & 15;
    const int rbase = (lane >> 4) * 4;
    #pragma unroll
    for (int n = 0; n < 4; ++n) {
        const int col = n*16 + cl;
        const float bias = b2[col];
        #pragma unroll
        for (int m = 0; m < 2; ++m) {
            #pragma unroll
            for (int rr = 0; rr < 4; ++rr) {
                const int grow = row0 + wid*32 + m*16 + rbase + rr;
                if (grow < NN)
                    zb[(size_t)grow * NCLS + col] = f2bf(acc[m][n][rr] + bias);
            }
        }
    }
}

// ---------------------------------------------------------------------------
// CSR build: histogram of dst over all 3 hops (int atomics to 400KB, L2-hot)
// ---------------------------------------------------------------------------
__global__ __launch_bounds__(256) void hist_kernel(const int* __restrict__ eidx,
                                                   int* __restrict__ deg) {
    const int t0 = blockIdx.x * 256 + threadIdx.x;
    const int stride = gridDim.x * 256;
    #pragma unroll
    for (int l = 0; l < NHOPS; ++l) {
        const int* dstp = eidx + (size_t)l * 2 * NE + NE;
        for (int e = t0; e < NE; e += stride)
            atomicAdd(&deg[dstp[e]], 1);
    }
}

// block sums (1024 elems/block)
__global__ __launch_bounds__(256) void scanA_kernel(const int* __restrict__ deg,
                                                    int* __restrict__ bsum) {
    const int tid = threadIdx.x;
    const int i0  = blockIdx.x * 1024 + tid * 4;
    int t = 0;
    #pragma unroll
    for (int k = 0; k < 4; ++k)
        if (i0 + k < NN) t += deg[i0 + k];
    #pragma unroll
    for (int off = 32; off; off >>= 1) t += __shfl_xor(t, off);
    __shared__ int wsum[4];
    if ((tid & 63) == 0) wsum[tid >> 6] = t;
    __syncthreads();
    if (tid == 0) bsum[blockIdx.x] = wsum[0] + wsum[1] + wsum[2] + wsum[3];
}

// exclusive scan of the 98 block sums; writes rowptr[NN] = total
__global__ __launch_bounds__(128) void scanB_kernel(int* __restrict__ bsum,
                                                    int* __restrict__ rowptr) {
    __shared__ int s[NBLK1];
    const int tid = threadIdx.x;
    if (tid < NBLK1) s[tid] = bsum[tid];
    __syncthreads();
    if (tid == 0) {
        int run = 0;
        for (int i = 0; i < NBLK1; ++i) { int v = s[i]; s[i] = run; run += v; }
        rowptr[NN] = run;
    }
    __syncthreads();
    if (tid < NBLK1) bsum[tid] = s[tid];
}

// full exclusive scan -> rowptr[0..NN-1] and cursor copy
__global__ __launch_bounds__(256) void scanC_kernel(const int* __restrict__ deg,
                                                    const int* __restrict__ bsum,
                                                    int* __restrict__ rowptr,
                                                    int* __restrict__ cursor) {
    __shared__ int tsum[256];
    const int tid = threadIdx.x;
    const int i0  = blockIdx.x * 1024 + tid * 4;
    int v[4];
    #pragma unroll
    for (int k = 0; k < 4; ++k)
        v[k] = (i0 + k < NN) ? deg[i0 + k] : 0;
    tsum[tid] = v[0] + v[1] + v[2] + v[3];
    __syncthreads();
    if (tid == 0) {
        int run = 0;
        for (int j = 0; j < 256; ++j) { int x = tsum[j]; tsum[j] = run; run += x; }
    }
    __syncthreads();
    int e = bsum[blockIdx.x] + tsum[tid];
    #pragma unroll
    for (int k = 0; k < 4; ++k) {
        if (i0 + k < NN) { rowptr[i0 + k] = e; cursor[i0 + k] = e; }
        e += v[k];
    }
}

// fill sorted edge arrays: srcs[pos], coefh[pos] = f16(pw[l+1]*att)
__global__ __launch_bounds__(256) void fill_kernel(
    const int* __restrict__ eidx, const float* __restrict__ att,
    const float* __restrict__ pw, int* __restrict__ cursor,
    int* __restrict__ srcs, _Float16* __restrict__ coefh)
{
    const int t0 = blockIdx.x * 256 + threadIdx.x;
    const int stride = gridDim.x * 256;
    #pragma unroll
    for (int l = 0; l < NHOPS; ++l) {
        const float w = pw[l + 1];
        const int* srcp = eidx + (size_t)l * 2 * NE;
        const int* dstp = srcp + NE;
        const float* al = att + (size_t)l * NE;
        for (int e = t0; e < NE; e += stride) {
            const int d  = dstp[e];
            const int pos = atomicAdd(&cursor[d], 1);
            srcs[pos]  = srcp[e];
            coefh[pos] = (_Float16)(w * al[e]);
        }
    }
}

// ---------------------------------------------------------------------------
// Accumulate (atomic-free) + fused log_softmax.
// One wave per node, lane = channel. 64 edges/chunk via shfl broadcast,
// 4 gathers in flight.
// ---------------------------------------------------------------------------
__global__ __launch_bounds__(256) void accum_kernel(
    const int* __restrict__ rowptr, const int* __restrict__ srcs,
    const _Float16* __restrict__ coefh, const u16* __restrict__ zb,
    const float* __restrict__ pw, float* __restrict__ out)
{
    const int lane = threadIdx.x & 63;
    const int node = blockIdx.x * 4 + (threadIdx.x >> 6);
    if (node >= NN) return;

    const int start = rowptr[node];
    const int end   = rowptr[node + 1];

    float a0 = pw[0] * bf2f(zb[(size_t)node * NCLS + lane]);
    float a1 = 0.f, a2 = 0.f, a3 = 0.f;

    for (int j = start; j < end; j += 64) {
        const int idx = j + lane;
        int   myS = 0; float myC = 0.f;
        if (idx < end) { myS = srcs[idx]; myC = (float)coefh[idx]; }
        const int cnt = min(64, end - j);
        int k = 0;
        for (; k + 4 <= cnt; k += 4) {
            int   s0 = __shfl(myS, k),     s1 = __shfl(myS, k + 1);
            int   s2 = __shfl(myS, k + 2), s3 = __shfl(myS, k + 3);
            float c0 = __shfl(myC, k),     c1 = __shfl(myC, k + 1);
            float c2 = __shfl(myC, k + 2), c3 = __shfl(myC, k + 3);
            float z0 = bf2f(zb[(size_t)s0 * NCLS + lane]);
            float z1 = bf2f(zb[(size_t)s1 * NCLS + lane]);
            float z2 = bf2f(zb[(size_t)s2 * NCLS + lane]);
            float z3 = bf2f(zb[(size_t)s3 * NCLS + lane]);
            a0 = fmaf(c0, z0, a0); a1 = fmaf(c1, z1, a1);
            a2 = fmaf(c2, z2, a2); a3 = fmaf(c3, z3, a3);
        }
        for (; k < cnt; ++k) {
            int   s = __shfl(myS, k);
            float c = __shfl(myC, k);
            a0 = fmaf(c, bf2f(zb[(size_t)s * NCLS + lane]), a0);
        }
    }
    const float v = (a0 + a1) + (a2 + a3);

    // log_softmax across the wave (C = 64)
    float m = v;
    #pragma unroll
    for (int off = 32; off; off >>= 1) m = fmaxf(m, __shfl_xor(m, off));
    float s = __expf(v - m);
    #pragma unroll
    for (int off = 32; off; off >>= 1) s += __shfl_xor(s, off);
    out[(size_t)node * NCLS + lane] = v - m - __logf(s);
}

// ---------------------------------------------------------------------------
extern "C" void kernel_launch(void* const* d_in, const int* in_sizes, int n_in,
                              void* d_out, int out_size, void* d_ws, size_t ws_size,
                              hipStream_t stream) {
    const float* x   = (const float*)d_in[0];
    const float* w1  = (const float*)d_in[1];
    const float* b1  = (const float*)d_in[2];
    const float* w2  = (const float*)d_in[3];
    const float* b2  = (const float*)d_in[4];
    const float* att = (const float*)d_in[5];
    const float* pw  = (const float*)d_in[6];
    const int* eidx  = (const int*)d_in[7];
    float* out = (float*)d_out;

    char* ws = (char*)d_ws;
    size_t off = 0;
    auto take = [&](size_t sz) { char* p = ws + off; off = (off + sz + 255) & ~(size_t)255; return p; };

    u16* w1t       = (u16*)take(F_IN * HID * 2);          // 0.26 MB
    u16* w2t       = (u16*)take(HID * NCLS * 2);          // 0.03 MB
    int* deg       = (int*)take(NN * 4);                  // 0.4 MB
    int* rowptr    = (int*)take((NN + 1) * 4);            // 0.4 MB
    int* cursor    = (int*)take(NN * 4);                  // 0.4 MB
    int* bsum      = (int*)take(NBLK1 * 4);
    u16* zb        = (u16*)take((size_t)NN * NCLS * 2);   // 12.8 MB
    u16* h         = (u16*)take((size_t)NN * HID * 2);    // 51.2 MB
    _Float16* coefh= (_Float16*)take((size_t)NHOPS * NE * 2); // 19.2 MB
    int* srcs      = (int*)h;   // alias: h dead after gemm2; 38.4 MB <= 51.2 MB

    hipMemsetAsync(deg, 0, NN * 4, stream);
    convert_weights<<<(F_IN*HID + HID*NCLS + 255) / 256, 256, 0, stream>>>(w1, w2, w1t, w2t);

    const int nblk_m = (NN + 127) / 128;                  // 782
    gemm1_kernel<<<nblk_m, 512, 0, stream>>>(x, w1t, b1, h);
    gemm2_kernel<<<nblk_m, 256, 0, stream>>>(h, w2t, b2, zb);

    hist_kernel <<<2048, 256, 0, stream>>>(eidx, deg);
    scanA_kernel<<<NBLK1, 256, 0, stream>>>(deg, bsum);
    scanB_kernel<<<1, 128, 0, stream>>>(bsum, rowptr);
    scanC_kernel<<<NBLK1, 256, 0, stream>>>(deg, bsum, rowptr, cursor);
    fill_kernel <<<2048, 256, 0, stream>>>(eidx, att, pw, cursor, srcs, coefh);  // after gemm2 (srcs aliases h)
    accum_kernel<<<(NN + 3) / 4, 256, 0, stream>>>(rowptr, srcs, coefh, zb, pw, out);
}